// Round 7
// baseline (381.617 us; speedup 1.0000x reference)
//
#include <hip/hip_runtime.h>

// PhotometricLoss: fused warp + SSIM(3x3 avgpool, zero-pad) + L1 + masked mean.
// B=8, C=3, H=720, W=1280 fp32.
//
// R10: channel-per-wave + rolled loop, no register cap.
// Session causal table: full-unroll combined-channel shuffle-gather = 172 VGPR
// no matter what (R7 free / R9 sched_barrier both 172); launch_bounds caps
// spill catastrophically (R8 437MB, R5/R6); sched_barrier(0) only worsens the
// schedule (R9: VALUBusy 31->24). Untested quadrant: ROLLED loop (structural
// bound on allocator live-ranges + scheduler motion), NO cap (no spill cliff),
// with per-iteration state shrunk by CHANNEL-SPLIT:
//   photo*valid = sum_c [a/3*ssim_c + (1-a)/3*l1_c]*valid  (exactly separable)
// Block = 192 thr = 3 waves; wave c handles channel c of the same strip/rows.
// Per step per wave: 4 loads (disp, left_c, 2 right-halo_c), 12-float ring,
// one SSIM emit. disp read 3x per block but same addrs on same CU -> L1/L2.
// Gather stays the proven register-shuffle (R7: duty 11%->37%, absmax=0):
// two 64-wide clamped coalesced halo loads (cols s0-8..s0+119), dynamic
// __shfl + select, border-exact; window-miss (P~1e-12/px) -> exact per-lane
// global fallback under __any.

#define P_ALPHA 0.85f
#define P_C1 1e-4f
#define P_C2 9e-4f

constexpr int COLS = 62;   // useful output columns per wave strip
constexpr int RPW  = 15;   // output rows per block (grid.y = 720/15 = 48)

__global__ __launch_bounds__(192)
void photo_loss_kernel(const float* __restrict__ disp,
                       const float* __restrict__ left,
                       const float* __restrict__ right,
                       float* __restrict__ acc,   // acc[0]=sum(photo*valid), acc[1]=sum(valid)
                       int H, int W)
{
    __shared__ float redpv[3];
    __shared__ float redv;

    const int tid  = threadIdx.x;
    const int lane = tid & 63;
    const int c    = tid >> 6;                              // wave index == channel
    const int b    = blockIdx.z;
    const int s0   = blockIdx.x * COLS;
    const int col  = s0 + lane - 1;                         // -1 .. W (+halo)
    const int rowStart = blockIdx.y * RPW;

    const int planeHW = H * W;
    const float* __restrict__ dispb = disp  + b * planeHW;
    const float* __restrict__ X = left  + (b * 3 + c) * planeHW;  // this wave's left ch
    const float* __restrict__ R = right + (b * 3 + c) * planeHW;  // this wave's right ch

    const float wm1f = (float)(W - 1);
    const float colf = (float)col;
    const int   colC = min(max(col, 0), W - 1);             // clamped address col
    const float colv = (col >= 0 && col < W) ? 1.f : 0.f;   // column validity
    const float ocm  = (lane >= 1 && lane <= COLS && col < W) ? 1.f : 0.f;  // output mask

    // halo columns this lane provides (clamped -> border-exact window values)
    const int colA = min(max(s0 - 8  + lane, 0), W - 1);    // window idx 0..63   = cols s0-8 .. s0+55
    const int colB = min(max(s0 + 56 + lane, 0), W - 1);    // window idx 64..127 = cols s0+56 .. s0+119

    // 2-slot stat ring for ONE channel: A = h[r-2], B = h[r-1]
    float Ax=0.f, Ay=0.f, Axx=0.f, Ayy=0.f, Axy=0.f;
    float Bx=0.f, By=0.f, Bxx=0.f, Byy=0.f, Bxy=0.f;
    float l1B=0.f, vB=0.f;

    float sum_pv = 0.f, sum_v = 0.f;

    #pragma unroll 2
    for (int j = 0; j < RPW + 2; ++j) {
        const int r  = rowStart - 1 + j;                    // row processed this step
        const int rc = min(max(r, 0), H - 1);
        const float rv = (r >= 0 && r < H) ? 1.f : 0.f;

        // ---- this step's 4 loads: all coalesced, all address-independent ----
        const int   off = rc * W + colC;
        const float d   = dispb[off];
        const float xc  = X[off];
        const int   ro  = rc * W;
        const float hA  = R[ro + colA];
        const float hB  = R[ro + colB];

        // ---- register gather via dynamic shuffle ----
        const float xs  = colf - d;
        const float xcl = fminf(fmaxf(xs, 0.f), wm1f);
        const float xf  = floorf(xcl);
        const float fr  = xcl - xf;
        const int   i0  = (int)xf;
        const int   k   = i0 - s0 + 8;       // index into 128-col window
        const int   k1  = k + 1;
        float g0, g1;
        {
            const float a  = __shfl(hA, k  & 63, 64), bb = __shfl(hB, k  & 63, 64);
            const float a1 = __shfl(hA, k1 & 63, 64), b1 = __shfl(hB, k1 & 63, 64);
            g0 = (k  < 64) ? a  : bb;
            g1 = (k1 < 64) ? a1 : b1;
        }
        // window miss (|disp| > ~70): exact per-lane global fallback, ~never taken
        const bool bad = (k < 0) || (k1 > 127);
        if (__builtin_expect(__any(bad), 0)) {
            if (bad) {
                const int i1 = min(i0 + 1, W - 1);
                g0 = R[ro + i0]; g1 = R[ro + i1];
            }
        }

        // ---- row-r values + horizontal stats (C) for this channel ----
        const float m  = rv * colv;
        const float y  = ((1.f - fr) * g0 + fr * g1) * m;
        const float x  = xc * m;
        const float xl = __shfl_up(x, 1, 64), xr = __shfl_down(x, 1, 64);
        const float yl = __shfl_up(y, 1, 64), yr = __shfl_down(y, 1, 64);
        const float Cx  = xl + x + xr;
        const float Cy  = yl + y + yr;
        const float Cxx = xl*xl + x*x + xr*xr;
        const float Cyy = yl*yl + y*y + yr*yr;
        const float Cxy = xl*yl + x*y + xr*yr;
        const float l1C = fabsf(x - y);
        const float vC  = (xs > 0.f && xs < wm1f) ? 1.f : 0.f;

        // ---- emit center r-1 using (A=h[r-2], B=h[r-1], C=h[r]) ----
        if (j >= 2) {                                       // wave-uniform branch
            const float inv9 = 1.f / 9.f;
            const float mu_x = (Ax  + Bx  + Cx)  * inv9;
            const float mu_y = (Ay  + By  + Cy)  * inv9;
            const float exx  = (Axx + Bxx + Cxx) * inv9;
            const float eyy  = (Ayy + Byy + Cyy) * inv9;
            const float exy  = (Axy + Bxy + Cxy) * inv9;
            const float sig_x  = fmaxf(exx - mu_x * mu_x, 0.f);
            const float sig_y  = fmaxf(eyy - mu_y * mu_y, 0.f);
            const float sig_xy = exy - mu_x * mu_y;
            const float n  = (2.f * mu_x * mu_y + P_C1) * (2.f * sig_xy + P_C2);
            const float dd = (mu_x * mu_x + mu_y * mu_y + P_C1) * (sig_x + sig_y + P_C2);
            float s = (1.f - n * __builtin_amdgcn_rcpf(dd)) * 0.5f;  // dd >= C1*C2 > 0
            s = fminf(fmaxf(s, 0.f), 1.f);
            // per-channel separable contribution: a/3*ssim_c + (1-a)/3*l1_c
            const float photo_c = (P_ALPHA * (1.f / 3.f)) * s
                                + ((1.f - P_ALPHA) * (1.f / 3.f)) * l1B;
            sum_pv += photo_c * vB * ocm;
            sum_v  += vB * ocm;                             // identical per ch; wave 0's used
        }

        // ---- ring shift (renamed away inside the unroll-2 pair) ----
        Ax = Bx; Ay = By; Axx = Bxx; Ayy = Byy; Axy = Bxy;
        Bx = Cx; By = Cy; Bxx = Cxx; Byy = Cyy; Bxy = Cxy;
        l1B = l1C; vB = vC;
    }

    // wave reduce (64 lanes) then cross-wave via tiny LDS
    #pragma unroll
    for (int o = 32; o > 0; o >>= 1) {
        sum_pv += __shfl_down(sum_pv, o, 64);
        sum_v  += __shfl_down(sum_v,  o, 64);
    }
    if (lane == 0) { redpv[c] = sum_pv; if (c == 0) redv = sum_v; }
    __syncthreads();
    if (tid == 0) {
        atomicAdd(&acc[0], redpv[0] + redpv[1] + redpv[2]);
        atomicAdd(&acc[1], redv);
    }
}

__global__ void photo_loss_finalize(const float* __restrict__ acc,
                                    float* __restrict__ out)
{
    out[0] = acc[0] / fmaxf(acc[1], 1.f);
}

extern "C" void kernel_launch(void* const* d_in, const int* in_sizes, int n_in,
                              void* d_out, int out_size, void* d_ws, size_t ws_size,
                              hipStream_t stream)
{
    const float* disp  = (const float*)d_in[0];
    const float* left  = (const float*)d_in[1];
    const float* right = (const float*)d_in[2];
    float* out = (float*)d_out;
    float* acc = (float*)d_ws;

    const int B = 8, H = 720, W = 1280;

    hipMemsetAsync(acc, 0, 2 * sizeof(float), stream);

    // x: 21 strips of 62 cols; y: 720/15 = 48 row-blocks; z: batch.
    // block = 192 threads = 3 waves (one per channel).
    dim3 grid((W + COLS - 1) / COLS, H / RPW, B);
    dim3 block(192);
    photo_loss_kernel<<<grid, block, 0, stream>>>(disp, left, right, acc, H, W);
    photo_loss_finalize<<<1, 1, 0, stream>>>(acc, out);
}

// Round 8
// 378.205 us; speedup vs baseline: 1.0090x; 1.0090x over previous
//
#include <hip/hip_runtime.h>

// PhotometricLoss: fused warp + SSIM(3x3 avgpool, zero-pad) + L1 + masked mean.
// B=8, C=3, H=720, W=1280 fp32.
//
// R11: channel-per-wave + FULL unroll (R10 with one token changed).
// Completed session law:
//   duty needs UNROLL (compiler load-hoisting across steps is the only
//   working prefetch on this compiler: R7 duty 37% vs rolled R10 duty 11%;
//   manual prefetch is sunk (R4) and sched_barrier only breaks scheduling (R9));
//   occupancy needs SMALL per-step state (R7's 10 loads/step -> 172 VGPR;
//   caps spill: R5/R6/R8).
// Channel-split gives small state (4 loads/step: disp, left_c, 2 right-halo_c;
// 12-float ring); R10 proved it compiles clean (68 VGPR, no spill) but tested
// it only rolled. Full unroll bounds the hoisting appetite structurally:
// 17 steps x 4 loads = 68 in-flight + 12 ring + ~25 misc ~= 110 VGPR
// -> 4 waves/SIMD, with R7-class duty -> VALU-issue-saturated, ~50us floor.
// Block = 192 thr = 3 waves; wave c = channel c of the same strip/rows.
//   photo*valid = sum_c [a/3*ssim_c + (1-a)/3*l1_c]*valid  (exactly separable)
// Gather: proven register-shuffle (R7/R10, absmax=0): two 64-wide clamped
// coalesced halo loads (cols s0-8..s0+119), dynamic __shfl + select,
// border-exact; window-miss -> exact per-lane global fallback under __any.

#define P_ALPHA 0.85f
#define P_C1 1e-4f
#define P_C2 9e-4f

constexpr int COLS = 62;   // useful output columns per wave strip
constexpr int RPW  = 15;   // output rows per block (grid.y = 720/15 = 48)

__global__ __launch_bounds__(192)
void photo_loss_kernel(const float* __restrict__ disp,
                       const float* __restrict__ left,
                       const float* __restrict__ right,
                       float* __restrict__ acc,   // acc[0]=sum(photo*valid), acc[1]=sum(valid)
                       int H, int W)
{
    __shared__ float redpv[3];
    __shared__ float redv;

    const int tid  = threadIdx.x;
    const int lane = tid & 63;
    const int c    = tid >> 6;                              // wave index == channel
    const int b    = blockIdx.z;
    const int s0   = blockIdx.x * COLS;
    const int col  = s0 + lane - 1;                         // -1 .. W (+halo)
    const int rowStart = blockIdx.y * RPW;

    const int planeHW = H * W;
    const float* __restrict__ dispb = disp  + b * planeHW;
    const float* __restrict__ X = left  + (b * 3 + c) * planeHW;  // this wave's left ch
    const float* __restrict__ R = right + (b * 3 + c) * planeHW;  // this wave's right ch

    const float wm1f = (float)(W - 1);
    const float colf = (float)col;
    const int   colC = min(max(col, 0), W - 1);             // clamped address col
    const float colv = (col >= 0 && col < W) ? 1.f : 0.f;   // column validity
    const float ocm  = (lane >= 1 && lane <= COLS && col < W) ? 1.f : 0.f;  // output mask

    // halo columns this lane provides (clamped -> border-exact window values)
    const int colA = min(max(s0 - 8  + lane, 0), W - 1);    // window idx 0..63   = cols s0-8 .. s0+55
    const int colB = min(max(s0 + 56 + lane, 0), W - 1);    // window idx 64..127 = cols s0+56 .. s0+119

    // 2-slot stat ring for ONE channel: A = h[r-2], B = h[r-1]
    float Ax=0.f, Ay=0.f, Axx=0.f, Ayy=0.f, Axy=0.f;
    float Bx=0.f, By=0.f, Bxx=0.f, Byy=0.f, Bxy=0.f;
    float l1B=0.f, vB=0.f;

    float sum_pv = 0.f, sum_v = 0.f;

    #pragma unroll
    for (int j = 0; j < RPW + 2; ++j) {
        const int r  = rowStart - 1 + j;                    // row processed this step
        const int rc = min(max(r, 0), H - 1);
        const float rv = (r >= 0 && r < H) ? 1.f : 0.f;

        // ---- this step's 4 loads: all coalesced, all address-independent ----
        const int   off = rc * W + colC;
        const float d   = dispb[off];
        const float xc  = X[off];
        const int   ro  = rc * W;
        const float hA  = R[ro + colA];
        const float hB  = R[ro + colB];

        // ---- register gather via dynamic shuffle ----
        const float xs  = colf - d;
        const float xcl = fminf(fmaxf(xs, 0.f), wm1f);
        const float xf  = floorf(xcl);
        const float fr  = xcl - xf;
        const int   i0  = (int)xf;
        const int   k   = i0 - s0 + 8;       // index into 128-col window
        const int   k1  = k + 1;
        float g0, g1;
        {
            const float a  = __shfl(hA, k  & 63, 64), bb = __shfl(hB, k  & 63, 64);
            const float a1 = __shfl(hA, k1 & 63, 64), b1 = __shfl(hB, k1 & 63, 64);
            g0 = (k  < 64) ? a  : bb;
            g1 = (k1 < 64) ? a1 : b1;
        }
        // window miss (|disp| > ~70): exact per-lane global fallback, ~never taken
        const bool bad = (k < 0) || (k1 > 127);
        if (__builtin_expect(__any(bad), 0)) {
            if (bad) {
                const int i1 = min(i0 + 1, W - 1);
                g0 = R[ro + i0]; g1 = R[ro + i1];
            }
        }

        // ---- row-r values + horizontal stats (C) for this channel ----
        const float m  = rv * colv;
        const float y  = ((1.f - fr) * g0 + fr * g1) * m;
        const float x  = xc * m;
        const float xl = __shfl_up(x, 1, 64), xr = __shfl_down(x, 1, 64);
        const float yl = __shfl_up(y, 1, 64), yr = __shfl_down(y, 1, 64);
        const float Cx  = xl + x + xr;
        const float Cy  = yl + y + yr;
        const float Cxx = xl*xl + x*x + xr*xr;
        const float Cyy = yl*yl + y*y + yr*yr;
        const float Cxy = xl*yl + x*y + xr*yr;
        const float l1C = fabsf(x - y);
        const float vC  = (xs > 0.f && xs < wm1f) ? 1.f : 0.f;

        // ---- emit center r-1 using (A=h[r-2], B=h[r-1], C=h[r]) ----
        if (j >= 2) {                                       // compile-time after unroll
            const float inv9 = 1.f / 9.f;
            const float mu_x = (Ax  + Bx  + Cx)  * inv9;
            const float mu_y = (Ay  + By  + Cy)  * inv9;
            const float exx  = (Axx + Bxx + Cxx) * inv9;
            const float eyy  = (Ayy + Byy + Cyy) * inv9;
            const float exy  = (Axy + Bxy + Cxy) * inv9;
            const float sig_x  = fmaxf(exx - mu_x * mu_x, 0.f);
            const float sig_y  = fmaxf(eyy - mu_y * mu_y, 0.f);
            const float sig_xy = exy - mu_x * mu_y;
            const float n  = (2.f * mu_x * mu_y + P_C1) * (2.f * sig_xy + P_C2);
            const float dd = (mu_x * mu_x + mu_y * mu_y + P_C1) * (sig_x + sig_y + P_C2);
            float s = (1.f - n * __builtin_amdgcn_rcpf(dd)) * 0.5f;  // dd >= C1*C2 > 0
            s = fminf(fmaxf(s, 0.f), 1.f);
            // per-channel separable contribution: a/3*ssim_c + (1-a)/3*l1_c
            const float photo_c = (P_ALPHA * (1.f / 3.f)) * s
                                + ((1.f - P_ALPHA) * (1.f / 3.f)) * l1B;
            sum_pv += photo_c * vB * ocm;
            sum_v  += vB * ocm;                             // identical per ch; wave 0's used
        }

        // ---- ring shift (pure renames under full unroll) ----
        Ax = Bx; Ay = By; Axx = Bxx; Ayy = Byy; Axy = Bxy;
        Bx = Cx; By = Cy; Bxx = Cxx; Byy = Cyy; Bxy = Cxy;
        l1B = l1C; vB = vC;
    }

    // wave reduce (64 lanes) then cross-wave via tiny LDS
    #pragma unroll
    for (int o = 32; o > 0; o >>= 1) {
        sum_pv += __shfl_down(sum_pv, o, 64);
        sum_v  += __shfl_down(sum_v,  o, 64);
    }
    if (lane == 0) { redpv[c] = sum_pv; if (c == 0) redv = sum_v; }
    __syncthreads();
    if (tid == 0) {
        atomicAdd(&acc[0], redpv[0] + redpv[1] + redpv[2]);
        atomicAdd(&acc[1], redv);
    }
}

__global__ void photo_loss_finalize(const float* __restrict__ acc,
                                    float* __restrict__ out)
{
    out[0] = acc[0] / fmaxf(acc[1], 1.f);
}

extern "C" void kernel_launch(void* const* d_in, const int* in_sizes, int n_in,
                              void* d_out, int out_size, void* d_ws, size_t ws_size,
                              hipStream_t stream)
{
    const float* disp  = (const float*)d_in[0];
    const float* left  = (const float*)d_in[1];
    const float* right = (const float*)d_in[2];
    float* out = (float*)d_out;
    float* acc = (float*)d_ws;

    const int B = 8, H = 720, W = 1280;

    hipMemsetAsync(acc, 0, 2 * sizeof(float), stream);

    // x: 21 strips of 62 cols; y: 720/15 = 48 row-blocks; z: batch.
    // block = 192 threads = 3 waves (one per channel).
    dim3 grid((W + COLS - 1) / COLS, H / RPW, B);
    dim3 block(192);
    photo_loss_kernel<<<grid, block, 0, stream>>>(disp, left, right, acc, H, W);
    photo_loss_finalize<<<1, 1, 0, stream>>>(acc, out);
}

// Round 9
// 245.868 us; speedup vs baseline: 1.5521x; 1.5382x over previous
//
#include <hip/hip_runtime.h>

// PhotometricLoss: fused warp + SSIM(3x3 avgpool, zero-pad) + L1 + masked mean.
// B=8, C=3, H=720, W=1280 fp32.
//
// R12: combined-channel shuffle-gather + EXPLICIT depth-2 software pipeline,
// rolled main loop, no register cap.
// Session law resolution (R11): R7's duty-37% came from its SOURCE-LEVEL
// prefetch being respected (shuffle-gather loads are independent -> compiler
// honors placement; dependent-gather prefetch gets sunk, R4). R10/R11 had no
// prefetch -> full latency exposed per step -> duty 11%. R8/R5/R6: any
// launch_bounds cap below appetite = catastrophic spill -> NO cap here;
// appetite is structurally bounded (ring 32 + 2x10 pipeline + misc ~ 110).
// Combined channels (not channel-split) to avoid the +45% VALU replication:
// total VALU-busy ~41us (R3) -> saturated target ~50-70us kernel.
// Pipeline: at step j consume row r (loaded 2 steps ago), issue row r+2.
// Slack = 2 steps ~ 2400 interleaved cycles >> 900cyc HBM latency.
// First two steps peeled -> emit guard is compile-time; hot loop has no
// branch except the never-taken __any window-miss fallback (P~1e-11/px,
// exact per-lane global fallback; absmax=0 across R7-R11).

#define P_ALPHA 0.85f
#define P_C1 1e-4f
#define P_C2 9e-4f

constexpr int COLS  = 62;   // useful output columns per wave strip
constexpr int RPW   = 15;   // output rows per wave (720 = 12*4*15)
constexpr int WAVES = 4;    // waves per block

__global__ __launch_bounds__(256)
void photo_loss_kernel(const float* __restrict__ disp,
                       const float* __restrict__ left,
                       const float* __restrict__ right,
                       float* __restrict__ acc,   // acc[0]=sum(photo*valid), acc[1]=sum(valid)
                       int H, int W)
{
    __shared__ float redpv[WAVES];
    __shared__ float redv[WAVES];

    const int tid  = threadIdx.x;
    const int lane = tid & 63;
    const int w    = tid >> 6;
    const int b    = blockIdx.z;
    const int s0   = blockIdx.x * COLS;
    const int col  = s0 + lane - 1;                         // -1 .. W (+halo)
    const int rowStart = (blockIdx.y * WAVES + w) * RPW;

    const int planeHW = H * W;
    const float* __restrict__ dispb = disp  + b * planeHW;
    const float* __restrict__ L0 = left  + (b * 3 + 0) * planeHW;
    const float* __restrict__ L1 = left  + (b * 3 + 1) * planeHW;
    const float* __restrict__ L2 = left  + (b * 3 + 2) * planeHW;
    const float* __restrict__ R0 = right + (b * 3 + 0) * planeHW;
    const float* __restrict__ R1 = right + (b * 3 + 1) * planeHW;
    const float* __restrict__ R2 = right + (b * 3 + 2) * planeHW;

    const float wm1f = (float)(W - 1);
    const float colf = (float)col;
    const int   colC = min(max(col, 0), W - 1);             // clamped address col
    const float colv = (col >= 0 && col < W) ? 1.f : 0.f;   // column validity
    const float ocm  = (lane >= 1 && lane <= COLS && col < W) ? 1.f : 0.f;  // output mask

    // halo columns this lane provides (clamped -> border-exact window values)
    const int colA = min(max(s0 - 8  + lane, 0), W - 1);    // window idx 0..63
    const int colB = min(max(s0 + 56 + lane, 0), W - 1);    // window idx 64..127

    // 2-slot combined-channel stat ring: A = h[r-2], B = h[r-1]
    float Ax0=0.f,Ay0=0.f,Axx0=0.f,Ayy0=0.f,Axy0=0.f;
    float Ax1=0.f,Ay1=0.f,Axx1=0.f,Ayy1=0.f,Axy1=0.f;
    float Ax2=0.f,Ay2=0.f,Axx2=0.f,Ayy2=0.f,Axy2=0.f;
    float Bx0=0.f,By0=0.f,Bxx0=0.f,Byy0=0.f,Bxy0=0.f;
    float Bx1=0.f,By1=0.f,Bxx1=0.f,Byy1=0.f,Bxy1=0.f;
    float Bx2=0.f,By2=0.f,Bxx2=0.f,Byy2=0.f,Bxy2=0.f;
    float l1B=0.f, vB=0.f;

    float sum_pv = 0.f, sum_v = 0.f;

    // issue one row's 10 independent coalesced loads into a named set
#define LOAD_ROW(ROW, D,X0,X1,X2,HA0,HA1,HA2,HB0,HB1,HB2) do {                 \
        const int rc_  = min(max((ROW), 0), H - 1);                            \
        const int off_ = rc_ * W + colC;                                       \
        D  = dispb[off_];                                                      \
        X0 = L0[off_]; X1 = L1[off_]; X2 = L2[off_];                           \
        const int ro_ = rc_ * W;                                               \
        HA0 = R0[ro_ + colA]; HB0 = R0[ro_ + colB];                            \
        HA1 = R1[ro_ + colA]; HB1 = R1[ro_ + colB];                            \
        HA2 = R2[ro_ + colA]; HB2 = R2[ro_ + colB];                            \
    } while (0)

    // consume one row's set: gather, stats, optional emit, ring shift
    auto STEP = [&](int r, bool doEmit,
                    float d, float xc0, float xc1, float xc2,
                    float hA0, float hA1, float hA2,
                    float hB0, float hB1, float hB2) {
        const float rv  = (r >= 0 && r < H) ? 1.f : 0.f;
        const float xs  = colf - d;
        const float xcl = fminf(fmaxf(xs, 0.f), wm1f);
        const float xf  = floorf(xcl);
        const float fr  = xcl - xf;
        const int   i0  = (int)xf;
        const int   k   = i0 - s0 + 8;       // index into 128-col window
        const int   k1  = k + 1;
        const int   ks  = k & 63;
        const int   k1s = k1 & 63;
        float g00, g01, g10, g11, g20, g21;
        {
            const float a  = __shfl(hA0, ks, 64),  bb = __shfl(hB0, ks, 64);
            const float a1 = __shfl(hA0, k1s, 64), b1 = __shfl(hB0, k1s, 64);
            g00 = (k  < 64) ? a  : bb;
            g01 = (k1 < 64) ? a1 : b1;
        }
        {
            const float a  = __shfl(hA1, ks, 64),  bb = __shfl(hB1, ks, 64);
            const float a1 = __shfl(hA1, k1s, 64), b1 = __shfl(hB1, k1s, 64);
            g10 = (k  < 64) ? a  : bb;
            g11 = (k1 < 64) ? a1 : b1;
        }
        {
            const float a  = __shfl(hA2, ks, 64),  bb = __shfl(hB2, ks, 64);
            const float a1 = __shfl(hA2, k1s, 64), b1 = __shfl(hB2, k1s, 64);
            g20 = (k  < 64) ? a  : bb;
            g21 = (k1 < 64) ? a1 : b1;
        }
        // window miss (|disp| > ~70): exact per-lane global fallback, ~never taken
        const bool bad = (k < 0) || (k1 > 127);
        if (__builtin_expect(__any(bad), 0)) {
            if (bad) {
                const int rc_ = min(max(r, 0), H - 1);
                const int ro_ = rc_ * W;
                const int i1  = min(i0 + 1, W - 1);
                g00 = R0[ro_ + i0]; g01 = R0[ro_ + i1];
                g10 = R1[ro_ + i0]; g11 = R1[ro_ + i1];
                g20 = R2[ro_ + i0]; g21 = R2[ro_ + i1];
            }
        }

        const float m   = rv * colv;
        const float omf = 1.f - fr;
        const float y0 = (omf * g00 + fr * g01) * m;
        const float y1 = (omf * g10 + fr * g11) * m;
        const float y2 = (omf * g20 + fr * g21) * m;
        const float x0 = xc0 * m;
        const float x1 = xc1 * m;
        const float x2 = xc2 * m;

        float Cx0,Cy0,Cxx0,Cyy0,Cxy0;
        float Cx1,Cy1,Cxx1,Cyy1,Cxy1;
        float Cx2,Cy2,Cxx2,Cyy2,Cxy2;
        {
            const float xl = __shfl_up(x0,1,64), xr = __shfl_down(x0,1,64);
            const float yl = __shfl_up(y0,1,64), yr = __shfl_down(y0,1,64);
            Cx0  = xl + x0 + xr;
            Cy0  = yl + y0 + yr;
            Cxx0 = xl*xl + x0*x0 + xr*xr;
            Cyy0 = yl*yl + y0*y0 + yr*yr;
            Cxy0 = xl*yl + x0*y0 + xr*yr;
        }
        {
            const float xl = __shfl_up(x1,1,64), xr = __shfl_down(x1,1,64);
            const float yl = __shfl_up(y1,1,64), yr = __shfl_down(y1,1,64);
            Cx1  = xl + x1 + xr;
            Cy1  = yl + y1 + yr;
            Cxx1 = xl*xl + x1*x1 + xr*xr;
            Cyy1 = yl*yl + y1*y1 + yr*yr;
            Cxy1 = xl*yl + x1*y1 + xr*yr;
        }
        {
            const float xl = __shfl_up(x2,1,64), xr = __shfl_down(x2,1,64);
            const float yl = __shfl_up(y2,1,64), yr = __shfl_down(y2,1,64);
            Cx2  = xl + x2 + xr;
            Cy2  = yl + y2 + yr;
            Cxx2 = xl*xl + x2*x2 + xr*xr;
            Cyy2 = yl*yl + y2*y2 + yr*yr;
            Cxy2 = xl*yl + x2*y2 + xr*yr;
        }
        const float l1C = fabsf(x0 - y0) + fabsf(x1 - y1) + fabsf(x2 - y2);
        const float vC  = (xs > 0.f && xs < wm1f) ? 1.f : 0.f;

        if (doEmit) {       // call-site constant -> folded, no runtime branch
            const float inv9 = 1.f / 9.f;
            float ssim_sum = 0.f;
            #define SSIM_CH(SX,SY,SXX,SYY,SXY)                                   \
            {                                                                    \
                const float mu_x = (A##SX + B##SX + C##SX) * inv9;               \
                const float mu_y = (A##SY + B##SY + C##SY) * inv9;               \
                const float exx  = (A##SXX + B##SXX + C##SXX) * inv9;            \
                const float eyy  = (A##SYY + B##SYY + C##SYY) * inv9;            \
                const float exy  = (A##SXY + B##SXY + C##SXY) * inv9;            \
                const float sig_x  = fmaxf(exx - mu_x * mu_x, 0.f);              \
                const float sig_y  = fmaxf(eyy - mu_y * mu_y, 0.f);              \
                const float sig_xy = exy - mu_x * mu_y;                          \
                const float n  = (2.f*mu_x*mu_y + P_C1) * (2.f*sig_xy + P_C2);   \
                const float dd = (mu_x*mu_x + mu_y*mu_y + P_C1)                  \
                               * (sig_x + sig_y + P_C2);                         \
                float s = (1.f - n * __builtin_amdgcn_rcpf(dd)) * 0.5f;          \
                s = fminf(fmaxf(s, 0.f), 1.f);                                   \
                ssim_sum += s;                                                   \
            }
            SSIM_CH(x0,y0,xx0,yy0,xy0)
            SSIM_CH(x1,y1,xx1,yy1,xy1)
            SSIM_CH(x2,y2,xx2,yy2,xy2)
            #undef SSIM_CH
            const float photo = P_ALPHA * (ssim_sum * (1.f / 3.f))
                              + (1.f - P_ALPHA) * (l1B * (1.f / 3.f));
            sum_pv += photo * vB * ocm;
            sum_v  += vB * ocm;
        }

        // ring shift
        Ax0=Bx0; Ay0=By0; Axx0=Bxx0; Ayy0=Byy0; Axy0=Bxy0;
        Ax1=Bx1; Ay1=By1; Axx1=Bxx1; Ayy1=Byy1; Axy1=Bxy1;
        Ax2=Bx2; Ay2=By2; Axx2=Bxx2; Ayy2=Byy2; Axy2=Bxy2;
        Bx0=Cx0; By0=Cy0; Bxx0=Cxx0; Byy0=Cyy0; Bxy0=Cxy0;
        Bx1=Cx1; By1=Cy1; Bxx1=Cxx1; Byy1=Cyy1; Bxy1=Cxy1;
        Bx2=Cx2; By2=Cy2; Bxx2=Cxx2; Byy2=Cyy2; Bxy2=Cxy2;
        l1B = l1C; vB = vC;
    };

    // ---- depth-2 pipeline: named sets c (row r) and n (row r+1) ----
    float cD,cX0,cX1,cX2,cA0,cA1,cA2,cB0,cB1,cB2;
    float nD,nX0,nX1,nX2,nA0,nA1,nA2,nB0,nB1,nB2;
    float tD,tX0,tX1,tX2,tA0,tA1,tA2,tB0,tB1,tB2;

    LOAD_ROW(rowStart - 1, cD,cX0,cX1,cX2,cA0,cA1,cA2,cB0,cB1,cB2);
    LOAD_ROW(rowStart,     nD,nX0,nX1,nX2,nA0,nA1,nA2,nB0,nB1,nB2);

#define ROTATE() do {                                                          \
        cD=nD; cX0=nX0; cX1=nX1; cX2=nX2;                                      \
        cA0=nA0; cA1=nA1; cA2=nA2; cB0=nB0; cB1=nB1; cB2=nB2;                  \
        nD=tD; nX0=tX0; nX1=tX1; nX2=tX2;                                      \
        nA0=tA0; nA1=tA1; nA2=tA2; nB0=tB0; nB1=tB1; nB2=tB2;                  \
    } while (0)

    // peeled j=0 (r=rowStart-1) and j=1 (r=rowStart): no emit
    LOAD_ROW(rowStart + 1, tD,tX0,tX1,tX2,tA0,tA1,tA2,tB0,tB1,tB2);
    STEP(rowStart - 1, false, cD,cX0,cX1,cX2,cA0,cA1,cA2,cB0,cB1,cB2);
    ROTATE();
    LOAD_ROW(rowStart + 2, tD,tX0,tX1,tX2,tA0,tA1,tA2,tB0,tB1,tB2);
    STEP(rowStart, false, cD,cX0,cX1,cX2,cA0,cA1,cA2,cB0,cB1,cB2);
    ROTATE();

    // main loop: 15 steps, r = rowStart+1 .. rowStart+RPW, emit center r-1
    #pragma unroll 3
    for (int j = 2; j <= RPW + 1; ++j) {
        const int r = rowStart - 1 + j;
        LOAD_ROW(r + 2, tD,tX0,tX1,tX2,tA0,tA1,tA2,tB0,tB1,tB2);  // clamped; tail rows harmless
        STEP(r, true, cD,cX0,cX1,cX2,cA0,cA1,cA2,cB0,cB1,cB2);
        ROTATE();
    }
#undef ROTATE
#undef LOAD_ROW

    // wave reduce (64 lanes) then cross-wave via tiny LDS
    #pragma unroll
    for (int off = 32; off > 0; off >>= 1) {
        sum_pv += __shfl_down(sum_pv, off, 64);
        sum_v  += __shfl_down(sum_v,  off, 64);
    }
    if (lane == 0) { redpv[w] = sum_pv; redv[w] = sum_v; }
    __syncthreads();
    if (tid == 0) {
        atomicAdd(&acc[0], redpv[0] + redpv[1] + redpv[2] + redpv[3]);
        atomicAdd(&acc[1], redv[0]  + redv[1]  + redv[2]  + redv[3]);
    }
}

__global__ void photo_loss_finalize(const float* __restrict__ acc,
                                    float* __restrict__ out)
{
    out[0] = acc[0] / fmaxf(acc[1], 1.f);
}

extern "C" void kernel_launch(void* const* d_in, const int* in_sizes, int n_in,
                              void* d_out, int out_size, void* d_ws, size_t ws_size,
                              hipStream_t stream)
{
    const float* disp  = (const float*)d_in[0];
    const float* left  = (const float*)d_in[1];
    const float* right = (const float*)d_in[2];
    float* out = (float*)d_out;
    float* acc = (float*)d_ws;

    const int B = 8, H = 720, W = 1280;

    hipMemsetAsync(acc, 0, 2 * sizeof(float), stream);

    // x: 21 strips of 62 cols; y: 720 / (4 waves * 15 rows) = 12; z: batch
    dim3 grid((W + COLS - 1) / COLS, H / (WAVES * RPW), B);
    dim3 block(256);
    photo_loss_kernel<<<grid, block, 0, stream>>>(disp, left, right, acc, H, W);
    photo_loss_finalize<<<1, 1, 0, stream>>>(acc, out);
}